// Round 9
// baseline (165.071 us; speedup 1.0000x reference)
//
#include <hip/hip_runtime.h>
#include <stdint.h>

// pairs_of_pairs: fused [concat -> conv1x1+relu x3]
// B=32, C=64, S=64, CC=128, OC=256. 2016 rows of 64 positions.
// R8 = R7 structure + WEIGHTS IN REGISTERS. Diagnosis R5-R7: kk-loop is
// load-latency-bound (4 global A-loads per 16 MFMA, ~300cyc L2 latency,
// 2-3 waves/SIMD of cover). Fix: each wave holds its layer's A (64o x 256k
// bf16 = 128 VGPR) in regs, loaded once per layer via 32 batched
// global_load_dwordx4; next layer's A-loads issue before the epilogue so the
// latency hides under h-write + barriers. kk-loop = pure ds_read_b128 + MFMA,
// fully unrolled (static aw indexing - rule #20). ~235 VGPR ->
// __launch_bounds__(256,1) (cap 256). LDS 32KB -> 2 blocks/CU.
// Layout (proven R7): layer-0 input = 3 regions [64pos][64ch] (rolled chunk
// aliased from x region at shifted pos); h overwrites all 32KB; bounce too.

typedef __attribute__((ext_vector_type(8))) __bf16 bf16x8;
typedef __attribute__((ext_vector_type(4))) float f32x4;
typedef __attribute__((ext_vector_type(4))) unsigned short u16x4;
typedef __attribute__((ext_vector_type(8))) unsigned short u16x8;

__device__ __forceinline__ unsigned short f2bf(float f) {
  unsigned int u = __builtin_bit_cast(unsigned int, f);
  u += 0x7FFFu + ((u >> 16) & 1u);
  return (unsigned short)(u >> 16);
}

// layer-0 regions: region r base = r*4096 elems; [64 pos][64 ch] swizzled:
// 16B-slot = p*8 + ((c6>>3)^p)&7.
__device__ __forceinline__ int xa(int reg, int p, int c6) {
  return reg * 4096 + (p * 8 + (((c6 >> 3) ^ p) & 7)) * 8 + (c6 & 7);
}
// h layout (layers 1-2 input): [64 pos][256 ch]: 16B-slot = p*32 + ((c>>3)^p)&31.
__device__ __forceinline__ int xh(int p, int c) {
  return (p * 32 + (((c >> 3) ^ p) & 31)) * 8 + (c & 7);
}

__global__ void wconv_kernel(const float* __restrict__ W1, const float* __restrict__ W2,
                             const float* __restrict__ W3, unsigned short* __restrict__ wb) {
  int i = (blockIdx.x * 256 + threadIdx.x) * 4;  // grid 64 -> 65536 per layer
  const float* Ws[3] = {W1, W2, W3};
#pragma unroll
  for (int L = 0; L < 3; ++L) {
    f32x4 a = *(const f32x4*)(Ws[L] + i);
    u16x4 p;
#pragma unroll
    for (int v = 0; v < 4; ++v) p[v] = f2bf(a[v]);
    *(u16x4*)(wb + L * 65536 + i) = p;
  }
}

__global__ __launch_bounds__(256, 1)
void fused_kernel(const float* __restrict__ x, const float* __restrict__ xc,
                  const unsigned short* __restrict__ wb,
                  const float* __restrict__ b1, const float* __restrict__ b2,
                  const float* __restrict__ b3, float* __restrict__ out) {
  __shared__ __align__(16) unsigned char lraw[32768];
  unsigned short* X = (unsigned short*)lraw;   // layer0 regions / h / bounce
  float* bounce = (float*)lraw;

  const int r = blockIdx.x;       // 0..2015
  const int b = r / 63;
  const int dd = r % 63;
  const int d = dd + 1;
  const int tid = threadIdx.x;    // 0..255
  const int lane = tid & 63;
  const int g16 = lane >> 4;
  const int l16 = lane & 15;
  const int wv = tid >> 6;        // wave 0..3, owns o in [wv*64, wv*64+64)
  const int ow = wv * 64;

  // A-weights in registers: aw[mf][kk] = 8 bf16 of row (ow+mf*16+l16),
  // k = kk*32 + g16*8 .. +8. 32 frags x 4 VGPR = 128 VGPR.
  bf16x8 aw[4][8];
  const unsigned short* wrow = wb + (ow + l16) * 256 + g16 * 8;
  auto aload = [&](int layer) {
    const unsigned short* wl = wrow + layer * 65536;
#pragma unroll
    for (int mf = 0; mf < 4; ++mf)
#pragma unroll
      for (int kk = 0; kk < 8; ++kk)
        aw[mf][kk] = __builtin_bit_cast(
            bf16x8, *(const u16x8*)(wl + mf * 16 * 256 + kk * 32));
  };

  aload(0);  // in flight under the build phase

  // ---------------- build layer-0 input (no staging) ----------------
#pragma unroll
  for (int cn = 0; cn < 3; ++cn) {        // 0: xc ch0-63, 1: xc ch64-127, 2: x
#pragma unroll
    for (int it = 0; it < 2; ++it) {
      int s = it * 256 + tid;             // 0..511
      int p = s & 63;
      int c0 = (s >> 6) << 3;             // 0,8,...,56
      u16x8 v;
#pragma unroll
      for (int j = 0; j < 8; ++j) {
        float f = (cn < 2) ? xc[(((b * 128 + cn * 64 + c0 + j) * 63) + dd) * 64 + p]
                           : x[(b * 64 + c0 + j) * 64 + p];
        v[j] = f2bf(f);
      }
      *(u16x8*)&X[xa(cn, p, c0)] = v;
    }
  }
  __syncthreads();

  // ---------------- 3 fused conv1x1+relu layers ----------------
  const float* biases[3] = {b1, b2, b3};
#pragma unroll
  for (int layer = 0; layer < 3; ++layer) {
    const float* bias = biases[layer];

    f32x4 acc[4][4] = {};                 // [mf][nf], wave tile = 64o x 64pos

#pragma unroll
    for (int kk = 0; kk < 8; ++kk) {      // FULL unroll: aw[.][kk] static
      int kb = kk * 32 + g16 * 8;
      bf16x8 bfr[4];
#pragma unroll
      for (int nf = 0; nf < 4; ++nf) {
        int p = nf * 16 + l16;            // position
        int addr;
        if (layer > 0)      addr = xh(p, kb);
        else if (kk < 2)    addr = xa(0, p, kb);
        else if (kk < 4)    addr = xa(1, p, kb - 64);
        else if (kk < 6)    addr = xa(2, p, kb - 128);
        else                addr = xa(2, (p - d) & 63, kb - 192);  // rolled x
        bfr[nf] = __builtin_bit_cast(bf16x8, *(const u16x8*)&X[addr]);
      }
#pragma unroll
      for (int mf = 0; mf < 4; ++mf)
#pragma unroll
        for (int nf = 0; nf < 4; ++nf)
          acc[mf][nf] = __builtin_amdgcn_mfma_f32_16x16x32_bf16(aw[mf][kk], bfr[nf], acc[mf][nf], 0, 0, 0);
    }

    if (layer < 2) aload(layer + 1);      // prefetch next layer's A; latency
                                          // hides under epilogue + barriers
    __syncthreads();  // all waves done reading X/h before overwrite

    if (layer < 2) {
      // bias + relu -> bf16 h into X (D frag: pos = l16 col, o = g16*4+v row)
#pragma unroll
      for (int mf = 0; mf < 4; ++mf) {
        int o0 = ow + mf * 16 + g16 * 4;
        f32x4 bv = *(const f32x4*)(bias + o0);
#pragma unroll
        for (int nf = 0; nf < 4; ++nf) {
          int p = nf * 16 + l16;
          u16x4 pk;
#pragma unroll
          for (int v = 0; v < 4; ++v)
            pk[v] = f2bf(fmaxf(acc[mf][nf][v] + bv[v], 0.f));
          *(u16x4*)&X[xh(p, o0)] = pk;
        }
      }
      __syncthreads();
    } else {
      // final: bias+relu -> fp32 bounce (LDS dead) -> f32x4 coalesced stores.
#pragma unroll
      for (int pass = 0; pass < 2; ++pass) {
        if (pass) __syncthreads();        // pass-0 reads done before pass-1 writes
        if ((wv >> 1) == pass) {
#pragma unroll
          for (int mf = 0; mf < 4; ++mf) {
            int oh0 = (wv & 1) * 64 + mf * 16 + g16 * 4;   // o - pass*128
            f32x4 bv = *(const f32x4*)(bias + pass * 128 + oh0);
#pragma unroll
            for (int nf = 0; nf < 4; ++nf) {
              int p = nf * 16 + l16;
#pragma unroll
              for (int v = 0; v < 4; ++v) {
                int oh = oh0 + v;
                bounce[oh * 64 + (p ^ ((oh & 7) << 2))] =
                    fmaxf(acc[mf][nf][v] + bv[v], 0.f);
              }
            }
          }
        }
        __syncthreads();
#pragma unroll
        for (int q = 0; q < 8; ++q) {
          int u = q * 256 + tid;          // 0..2047
          int oh = u >> 4;                // 0..127
          int p4 = (u & 15) << 2;
          f32x4 vv = *(const f32x4*)&bounce[oh * 64 + (p4 ^ ((oh & 7) << 2))];
          *(f32x4*)&out[(((b * 256 + pass * 128 + oh) * 63) + dd) * 64 + p4] = vv;
        }
      }
    }
  }
}

extern "C" void kernel_launch(void* const* d_in, const int* in_sizes, int n_in,
                              void* d_out, int out_size, void* d_ws, size_t ws_size,
                              hipStream_t stream) {
  const float* x  = (const float*)d_in[0];
  const float* xc = (const float*)d_in[1];
  const float* W1 = (const float*)d_in[2];
  const float* b1 = (const float*)d_in[3];
  const float* W2 = (const float*)d_in[4];
  const float* b2 = (const float*)d_in[5];
  const float* W3 = (const float*)d_in[6];
  const float* b3 = (const float*)d_in[7];
  float* out = (float*)d_out;
  unsigned short* wb = (unsigned short*)d_ws;  // 3 x 256 x 256 bf16 = 384 KB

  wconv_kernel<<<64, 256, 0, stream>>>(W1, W2, W3, wb);
  fused_kernel<<<2016, 256, 0, stream>>>(x, xc, wb, b1, b2, b3, out);
}

// Round 10
// 110.254 us; speedup vs baseline: 1.4972x; 1.4972x over previous
//
#include <hip/hip_runtime.h>
#include <stdint.h>

// pairs_of_pairs: fused [concat -> conv1x1+relu x3]
// B=32, C=64, S=64, CC=128, OC=256. 2016 rows of 64 positions.
// R9 = R5 (best, 122us) + XCD-chunked block swizzle ONLY.
// Theory: xc reads / out writes are 256B chunks at 4-16KB stride; default
// round-robin dispatch puts consecutive-dd blocks (adjacent 256B lines) on
// DIFFERENT XCDs -> DRAM page thrash. Chunked swizzle r=(bid%8)*126+bid/8
// gives each XCD ~32 consecutive row-ids concurrently -> contiguous DRAM runs.
// Structure (R5): 2 rows/block (b0, b0+16), 512 thr, 8 waves of 32o x 128pos,
// LDS 64KB (X = 4 chunk regions [128pos][64ch], rolled chunk aliased, stg
// double-buffer in chunk3 region), __launch_bounds__(512,2) (VGPR cap 128,
// natural 104, no spill).

typedef __attribute__((ext_vector_type(8))) __bf16 bf16x8;
typedef __attribute__((ext_vector_type(4))) float f32x4;
typedef __attribute__((ext_vector_type(4))) unsigned short u16x4;
typedef __attribute__((ext_vector_type(8))) unsigned short u16x8;

__device__ __forceinline__ unsigned short f2bf(float f) {
  unsigned int u = __builtin_bit_cast(unsigned int, f);
  u += 0x7FFFu + ((u >> 16) & 1u);
  return (unsigned short)(u >> 16);
}

// X: 4 chunk regions of [128 pos][64 ch] bf16 (8192 elems each).
// Within chunk: 16B-slot = pos*8 + ((c6/8) ^ (pos&7)) -> max 2-way (free).
__device__ __forceinline__ int xaddr(int pos, int c) {
  int slot = (pos << 3) + ((((c & 63) >> 3) ^ pos) & 7);
  return ((c >> 6) << 13) + (slot << 3) + (c & 7);
}

__global__ void wconv_kernel(const float* __restrict__ W1, const float* __restrict__ W2,
                             const float* __restrict__ W3, unsigned short* __restrict__ wb) {
  int i = (blockIdx.x * 256 + threadIdx.x) * 4;  // grid 64 -> 65536 per layer
  const float* Ws[3] = {W1, W2, W3};
#pragma unroll
  for (int L = 0; L < 3; ++L) {
    f32x4 a = *(const f32x4*)(Ws[L] + i);
    u16x4 p;
#pragma unroll
    for (int v = 0; v < 4; ++v) p[v] = f2bf(a[v]);
    *(u16x4*)(wb + L * 65536 + i) = p;
  }
}

__global__ __launch_bounds__(512, 2)
void fused_kernel(const float* __restrict__ x, const float* __restrict__ xc,
                  const unsigned short* __restrict__ wb,
                  const float* __restrict__ b1, const float* __restrict__ b2,
                  const float* __restrict__ b3, float* __restrict__ out) {
  __shared__ __align__(16) unsigned char lraw[65536];
  unsigned short* X = (unsigned short*)lraw;                // 64KB, 4 chunks
  float* bounce = (float*)lraw;                             // 32KB epilogue reuse
  unsigned short* stg0 = (unsigned short*)(lraw + 49152);   // 8KB, in chunk3 region
  unsigned short* stg1 = (unsigned short*)(lraw + 57344);   // 8KB, in chunk3 region

  // XCD-chunked swizzle: dispatch id i -> XCD i%8 (round-robin). Give XCD k
  // the consecutive logical rows [126k, 126k+126) so concurrent blocks on one
  // XCD touch adjacent 256B lines of xc and out. 1008 = 8*126, bijective.
  const int bid = blockIdx.x;
  const int r = (bid & 7) * 126 + (bid >> 3);   // 0..1007
  const int b0 = r / 63;          // 0..15 ; row1 uses b0+16
  const int dd = r % 63;
  const int d = dd + 1;
  const int tid = threadIdx.x;    // 0..511
  const int lane = tid & 63;
  const int g16 = lane >> 4;
  const int l16 = lane & 15;
  const int wv = tid >> 6;        // wave 0..7

  // ---------------- build layer-0 input tiles (2 rows, 6 rounds) ----------
  // round rd: rr = rd/3 (row), ck = rd%3 (0: xc ch0-63, 1: xc ch64-127, 2: x).
  // stg double-buffered -> 1 barrier/round. No rolled chunk stored.
  auto ldrnd = [&](int rd, f32x4 ld[2]) {
    int rr = rd / 3;
    int ck = rd - rr * 3;
    int b = b0 + 16 * rr;
#pragma unroll
    for (int it = 0; it < 2; ++it) {
      int u = it * 512 + tid, cc = u >> 4, i4 = (u & 15) << 2;
      const float* src = (ck < 2)
          ? xc + (((b * 128 + ck * 64 + cc) * 63) + dd) * 64 + i4
          : x + (b * 64 + cc) * 64 + i4;
      ld[it] = *(const f32x4*)src;
    }
  };

  f32x4 ld[2];
  ldrnd(0, ld);
  for (int rd = 0; rd < 6; ++rd) {
    unsigned short* sb = (rd & 1) ? stg1 : stg0;
#pragma unroll
    for (int it = 0; it < 2; ++it) {   // regs -> stg (bf16 [c][i])
      int u = it * 512 + tid, cc = u >> 4, i4 = (u & 15) << 2;
      u16x4 p;
#pragma unroll
      for (int v = 0; v < 4; ++v) p[v] = f2bf(ld[it][v]);
      *(u16x4*)&sb[cc * 64 + i4] = p;
    }
    if (rd < 5) ldrnd(rd + 1, ld);     // prefetch next round's globals
    __syncthreads();
    // transpose sb -> X chunk ck, rows [rr*64, rr*64+64)
    {
      int rr = rd / 3;
      int ck = rd - rr * 3;
      int i = tid & 63;                // position within row
      int c0 = (tid >> 6) << 3;        // 0,8,...,56
      u16x8 p;
#pragma unroll
      for (int j = 0; j < 8; ++j) p[j] = sb[(c0 + j) * 64 + i];
      *(u16x8*)&X[xaddr(rr * 64 + i, ck * 64 + c0)] = p;
    }
  }
  __syncthreads();  // build complete before layer-0 reads

  // ---------------- 3 fused conv1x1+relu layers ----------------
  for (int layer = 0; layer < 3; ++layer) {
    const unsigned short* wl = wb + layer * 65536;
    const float* bias = (layer == 0) ? b1 : (layer == 1) ? b2 : b3;
    const bool al3 = (layer == 0);     // layer 0: k in [192,256) aliases chunk2 shifted

    f32x4 acc[2][8] = {};              // [mf][nf], wave tile = 32 o x 128 pos
    const int ow = wv * 32;

#pragma unroll 2
    for (int kk = 0; kk < 8; ++kk) {
      int kb = kk * 32 + g16 * 8;      // this lane-group's k-base
      bool a3 = al3 && (kk >= 6);
      int cc = a3 ? (128 + (kb & 63)) : kb;  // aliased -> chunk2 region
      bf16x8 afr[2];
#pragma unroll
      for (int mf = 0; mf < 2; ++mf)
        afr[mf] = __builtin_bit_cast(
            bf16x8, *(const u16x8*)(wl + (ow + mf * 16 + l16) * 256 + kb));
      bf16x8 bfr[4];
#pragma unroll
      for (int nf = 0; nf < 4; ++nf) { // row0 positions 0..63
        int i = nf * 16 + l16;
        int ie = a3 ? ((i - d) & 63) : i;
        bfr[nf] = __builtin_bit_cast(bf16x8, *(const u16x8*)&X[xaddr(ie, cc)]);
      }
#pragma unroll
      for (int mf = 0; mf < 2; ++mf)
#pragma unroll
        for (int nf = 0; nf < 4; ++nf)
          acc[mf][nf] = __builtin_amdgcn_mfma_f32_16x16x32_bf16(afr[mf], bfr[nf], acc[mf][nf], 0, 0, 0);
#pragma unroll
      for (int nf = 0; nf < 4; ++nf) { // row1 positions 64..127
        int i = nf * 16 + l16;
        int ie = 64 + (a3 ? ((i - d) & 63) : i);
        bfr[nf] = __builtin_bit_cast(bf16x8, *(const u16x8*)&X[xaddr(ie, cc)]);
      }
#pragma unroll
      for (int mf = 0; mf < 2; ++mf)
#pragma unroll
        for (int nf = 0; nf < 4; ++nf)
          acc[mf][4 + nf] = __builtin_amdgcn_mfma_f32_16x16x32_bf16(afr[mf], bfr[nf], acc[mf][4 + nf], 0, 0, 0);
    }
    __syncthreads();  // all waves done reading X before it is overwritten

    if (layer < 2) {
      // bias + relu -> bf16 back into X (D frag: pos = l16 col, o = g16*4+v)
#pragma unroll
      for (int mf = 0; mf < 2; ++mf) {
        int o0 = ow + mf * 16 + g16 * 4;
        f32x4 bv = *(const f32x4*)(bias + o0);
#pragma unroll
        for (int nf = 0; nf < 8; ++nf) {
          int pos = nf * 16 + l16;     // 0..127 covers both rows
          u16x4 p;
#pragma unroll
          for (int v = 0; v < 4; ++v)
            p[v] = f2bf(fmaxf(acc[mf][nf][v] + bv[v], 0.f));
          *(u16x4*)&X[xaddr(pos, o0)] = p;
        }
      }
      __syncthreads();
    } else {
      // final: bias+relu -> fp32 LDS bounce (X dead) -> f32x4 stores.
      // 4 rounds (rr,h): row rr, o in [h*128, h*128+128). Waves wv>>2==h write.
      bool first = true;
#pragma unroll
      for (int rr = 0; rr < 2; ++rr) {
#pragma unroll
        for (int h = 0; h < 2; ++h) {
          if (!first) __syncthreads();   // prev round's reads done
          first = false;
          if ((wv >> 2) == h) {
#pragma unroll
            for (int mf = 0; mf < 2; ++mf) {
              int olb = (wv & 3) * 32 + mf * 16 + g16 * 4;  // o - h*128
              f32x4 bv = *(const f32x4*)(bias + h * 128 + olb);
#pragma unroll
              for (int nq = 0; nq < 4; ++nq) {
                int pos = nq * 16 + l16;  // within-row position
#pragma unroll
                for (int v = 0; v < 4; ++v) {
                  int ol = olb + v;
                  bounce[ol * 64 + (pos ^ ((ol & 7) << 2))] =
                      fmaxf(acc[mf][rr * 4 + nq][v] + bv[v], 0.f);
                }
              }
            }
          }
          __syncthreads();
          // read back along pos, coalesced f32x4 global stores
          int bq = b0 + 16 * rr;
#pragma unroll
          for (int q = 0; q < 4; ++q) {
            int u = q * 512 + tid;
            int oh = u >> 4;             // 0..127
            int pos4 = (u & 15) << 2;
            f32x4 vv = *(const f32x4*)&bounce[oh * 64 + (pos4 ^ ((oh & 7) << 2))];
            int o = h * 128 + oh;
            *(f32x4*)&out[(((bq * 256 + o) * 63) + dd) * 64 + pos4] = vv;
          }
        }
      }
    }
  }
}

extern "C" void kernel_launch(void* const* d_in, const int* in_sizes, int n_in,
                              void* d_out, int out_size, void* d_ws, size_t ws_size,
                              hipStream_t stream) {
  const float* x  = (const float*)d_in[0];
  const float* xc = (const float*)d_in[1];
  const float* W1 = (const float*)d_in[2];
  const float* b1 = (const float*)d_in[3];
  const float* W2 = (const float*)d_in[4];
  const float* b2 = (const float*)d_in[5];
  const float* W3 = (const float*)d_in[6];
  const float* b3 = (const float*)d_in[7];
  float* out = (float*)d_out;
  unsigned short* wb = (unsigned short*)d_ws;  // 3 x 256 x 256 bf16 = 384 KB

  wconv_kernel<<<64, 256, 0, stream>>>(W1, W2, W3, wb);
  fused_kernel<<<1008, 512, 0, stream>>>(x, xc, wb, b1, b2, b3, out);
}

// Round 11
// 106.134 us; speedup vs baseline: 1.5553x; 1.0388x over previous
//
#include <hip/hip_runtime.h>
#include <stdint.h>

// pairs_of_pairs: fused [concat -> conv1x1+relu x3]
// B=32, C=64, S=64, CC=128, OC=256. 2016 rows of 64 positions.
// R10 = R5 compute structure with the barrier chain cut 18 -> 10.
// Evidence: R5 block = ~75K cycles vs ~40K of pipe work; every pipe <=25%;
// 1 block/CU (64KB LDS, pool <128KB) means barrier drains are raw latency.
// Changes vs R5:
//  (1) build = R7-style direct global->reg->swizzled ds_write_b128,
//      1 barrier (was 7); no stg buffers, no scalar LDS transpose reads.
//  (2) L3 epilogue bounce uses full 64KB (X dead) -> 1 round per row, all
//      8 waves write concurrently; 5 barriers (was 9).
// Kept: 2 rows/block (b0,b0+16), 512 thr, 8 waves x 32o x 128pos, kk-loop
// with 2 A-loads : 16 MFMA, xaddr chunk swizzle, rolled chunk aliased from
// chunk2 at shifted pos, __launch_bounds__(512,2) (VGPR cap 128, no spill).

typedef __attribute__((ext_vector_type(8))) __bf16 bf16x8;
typedef __attribute__((ext_vector_type(4))) float f32x4;
typedef __attribute__((ext_vector_type(4))) unsigned short u16x4;
typedef __attribute__((ext_vector_type(8))) unsigned short u16x8;

__device__ __forceinline__ unsigned short f2bf(float f) {
  unsigned int u = __builtin_bit_cast(unsigned int, f);
  u += 0x7FFFu + ((u >> 16) & 1u);
  return (unsigned short)(u >> 16);
}

// X: 4 chunk regions of [128 pos][64 ch] bf16 (8192 elems each).
// Within chunk: 16B-slot = pos*8 + ((c6/8) ^ (pos&7)) -> max 2-way (free).
__device__ __forceinline__ int xaddr(int pos, int c) {
  int slot = (pos << 3) + ((((c & 63) >> 3) ^ pos) & 7);
  return ((c >> 6) << 13) + (slot << 3) + (c & 7);
}

__global__ void wconv_kernel(const float* __restrict__ W1, const float* __restrict__ W2,
                             const float* __restrict__ W3, unsigned short* __restrict__ wb) {
  int i = (blockIdx.x * 256 + threadIdx.x) * 4;  // grid 64 -> 65536 per layer
  const float* Ws[3] = {W1, W2, W3};
#pragma unroll
  for (int L = 0; L < 3; ++L) {
    f32x4 a = *(const f32x4*)(Ws[L] + i);
    u16x4 p;
#pragma unroll
    for (int v = 0; v < 4; ++v) p[v] = f2bf(a[v]);
    *(u16x4*)(wb + L * 65536 + i) = p;
  }
}

__global__ __launch_bounds__(512, 2)
void fused_kernel(const float* __restrict__ x, const float* __restrict__ xc,
                  const unsigned short* __restrict__ wb,
                  const float* __restrict__ b1, const float* __restrict__ b2,
                  const float* __restrict__ b3, float* __restrict__ out) {
  __shared__ __align__(16) unsigned char lraw[65536];
  unsigned short* X = (unsigned short*)lraw;   // 64KB, 4 chunk regions
  float* bounce = (float*)lraw;                // full 64KB epilogue reuse

  const int r = blockIdx.x;       // 0..1007
  const int b0 = r / 63;          // 0..15 ; row1 uses b0+16
  const int dd = r % 63;
  const int d = dd + 1;
  const int tid = threadIdx.x;    // 0..511
  const int lane = tid & 63;
  const int g16 = lane >> 4;
  const int l16 = lane & 15;
  const int wv = tid >> 6;        // wave 0..7

  // ---------------- build: direct global -> swizzled LDS, 1 barrier --------
  // Thread owns (p = tid&63, c-octet c0 = (tid>>6)*8). For each of 6
  // chunk-rows (rr=row, ck=chunk): 8 coalesced f32 loads (lanes = consecutive
  // pos, 256B segments) -> bf16 pack -> 1 swizzled ds_write_b128.
  {
    const int p = tid & 63;
    const int c0 = (tid >> 6) << 3;   // 0,8,...,56
#pragma unroll
    for (int cr = 0; cr < 6; ++cr) {
      const int rr = cr / 3;
      const int ck = cr - rr * 3;
      const int b = b0 + 16 * rr;
      u16x8 v;
#pragma unroll
      for (int j = 0; j < 8; ++j) {
        float f = (ck < 2) ? xc[(((b * 128 + ck * 64 + c0 + j) * 63) + dd) * 64 + p]
                           : x[(b * 64 + c0 + j) * 64 + p];
        v[j] = f2bf(f);
      }
      *(u16x8*)&X[xaddr(rr * 64 + p, ck * 64 + c0)] = v;
    }
  }
  __syncthreads();

  // ---------------- 3 fused conv1x1+relu layers ----------------
  for (int layer = 0; layer < 3; ++layer) {
    const unsigned short* wl = wb + layer * 65536;
    const float* bias = (layer == 0) ? b1 : (layer == 1) ? b2 : b3;
    const bool al3 = (layer == 0);     // layer 0: k in [192,256) aliases chunk2 shifted

    f32x4 acc[2][8] = {};              // [mf][nf], wave tile = 32 o x 128 pos
    const int ow = wv * 32;

#pragma unroll 2
    for (int kk = 0; kk < 8; ++kk) {
      int kb = kk * 32 + g16 * 8;      // this lane-group's k-base
      bool a3 = al3 && (kk >= 6);
      int cc = a3 ? (128 + (kb & 63)) : kb;  // aliased -> chunk2 region
      bf16x8 afr[2];
#pragma unroll
      for (int mf = 0; mf < 2; ++mf)
        afr[mf] = __builtin_bit_cast(
            bf16x8, *(const u16x8*)(wl + (ow + mf * 16 + l16) * 256 + kb));
      bf16x8 bfr[4];
#pragma unroll
      for (int nf = 0; nf < 4; ++nf) { // row0 positions 0..63
        int i = nf * 16 + l16;
        int ie = a3 ? ((i - d) & 63) : i;
        bfr[nf] = __builtin_bit_cast(bf16x8, *(const u16x8*)&X[xaddr(ie, cc)]);
      }
#pragma unroll
      for (int mf = 0; mf < 2; ++mf)
#pragma unroll
        for (int nf = 0; nf < 4; ++nf)
          acc[mf][nf] = __builtin_amdgcn_mfma_f32_16x16x32_bf16(afr[mf], bfr[nf], acc[mf][nf], 0, 0, 0);
#pragma unroll
      for (int nf = 0; nf < 4; ++nf) { // row1 positions 64..127
        int i = nf * 16 + l16;
        int ie = 64 + (a3 ? ((i - d) & 63) : i);
        bfr[nf] = __builtin_bit_cast(bf16x8, *(const u16x8*)&X[xaddr(ie, cc)]);
      }
#pragma unroll
      for (int mf = 0; mf < 2; ++mf)
#pragma unroll
        for (int nf = 0; nf < 4; ++nf)
          acc[mf][4 + nf] = __builtin_amdgcn_mfma_f32_16x16x32_bf16(afr[mf], bfr[nf], acc[mf][4 + nf], 0, 0, 0);
    }
    __syncthreads();  // all waves done reading X before it is overwritten

    if (layer < 2) {
      // bias + relu -> bf16 back into X (D frag: pos = l16 col, o = g16*4+v)
#pragma unroll
      for (int mf = 0; mf < 2; ++mf) {
        int o0 = ow + mf * 16 + g16 * 4;
        f32x4 bv = *(const f32x4*)(bias + o0);
#pragma unroll
        for (int nf = 0; nf < 8; ++nf) {
          int pos = nf * 16 + l16;     // 0..127 covers both rows
          u16x4 p;
#pragma unroll
          for (int v = 0; v < 4; ++v)
            p[v] = f2bf(fmaxf(acc[mf][nf][v] + bv[v], 0.f));
          *(u16x4*)&X[xaddr(pos, o0)] = p;
        }
      }
      __syncthreads();
    } else {
      // final: bias+relu -> fp32 bounce over FULL 64KB (X dead) -> f32x4
      // stores. One round per row; all 8 waves write their 32-o slice.
#pragma unroll
      for (int rr = 0; rr < 2; ++rr) {
#pragma unroll
        for (int mf = 0; mf < 2; ++mf) {
          int oh0 = ow + mf * 16 + g16 * 4;      // 0..255
          f32x4 bv = *(const f32x4*)(bias + oh0);
#pragma unroll
          for (int nq = 0; nq < 4; ++nq) {
            int pos = nq * 16 + l16;             // within-row position
#pragma unroll
            for (int v = 0; v < 4; ++v) {
              int oh = oh0 + v;
              bounce[oh * 64 + (pos ^ ((oh & 7) << 2))] =
                  fmaxf(acc[mf][rr * 4 + nq][v] + bv[v], 0.f);
            }
          }
        }
        __syncthreads();
        // read back along pos, coalesced f32x4 global stores (64KB = 8/thread)
        int bq = b0 + 16 * rr;
#pragma unroll
        for (int q = 0; q < 8; ++q) {
          int u = q * 512 + tid;                 // 0..4095
          int oh = u >> 4;                       // 0..255
          int pos4 = (u & 15) << 2;
          f32x4 vv = *(const f32x4*)&bounce[oh * 64 + (pos4 ^ ((oh & 7) << 2))];
          *(f32x4*)&out[(((bq * 256 + oh) * 63) + dd) * 64 + pos4] = vv;
        }
        if (rr == 0) __syncthreads();            // row0 reads done before row1 writes
      }
    }
  }
}

extern "C" void kernel_launch(void* const* d_in, const int* in_sizes, int n_in,
                              void* d_out, int out_size, void* d_ws, size_t ws_size,
                              hipStream_t stream) {
  const float* x  = (const float*)d_in[0];
  const float* xc = (const float*)d_in[1];
  const float* W1 = (const float*)d_in[2];
  const float* b1 = (const float*)d_in[3];
  const float* W2 = (const float*)d_in[4];
  const float* b2 = (const float*)d_in[5];
  const float* W3 = (const float*)d_in[6];
  const float* b3 = (const float*)d_in[7];
  float* out = (float*)d_out;
  unsigned short* wb = (unsigned short*)d_ws;  // 3 x 256 x 256 bf16 = 384 KB

  wconv_kernel<<<64, 256, 0, stream>>>(W1, W2, W3, wb);
  fused_kernel<<<1008, 512, 0, stream>>>(x, xc, wb, b1, b2, b3, out);
}